// Round 1
// baseline (983.303 us; speedup 1.0000x reference)
//
#include <hip/hip_runtime.h>
#include <math.h>

#define N_NODES 100000
#define N_EDGES 800000
#define D_IN    64
#define HC      128   // H*C
#define CAP     48    // max in-degree slots (Poisson(8): P(>48) ~ 0)

// tanh-approx gelu (jax.nn.gelu default approximate=True)
__device__ __forceinline__ float gelu_f(float x) {
    float x3 = x * x * x;
    float y  = 0.7978845608028654f * (x + 0.044715f * x3);
    // tanh(y) = 1 - 2/(exp(2y)+1)
    float t = 1.0f - 2.0f / (__expf(2.0f * y) + 1.0f);
    return 0.5f * x * (1.0f + t);
}

// ---------------- CSR-by-capacity scatter (once; shared by both layers) ----
__global__ void scatter_kernel(const int* __restrict__ edges,
                               int* __restrict__ cnt, int* __restrict__ tbl) {
    int e = blockIdx.x * blockDim.x + threadIdx.x;
    if (e >= N_EDGES) return;
    int s = edges[e];            // src row
    int d = edges[N_EDGES + e];  // dst row
    int slot = atomicAdd(&cnt[d], 1);
    if (slot < CAP) tbl[d * CAP + slot] = s;
}

// ---------------- xl/xr GEMM: [N,64] @ [64,128] + b -------------------------
// 128 threads/block; blockIdx parity selects (Wl,bl->XL) or (Wr,br->XR).
// Each block: 256 nodes (2 per thread) x 128 cols. W^T staged in LDS,
// stride 68 floats: 16B-aligned rows for ds_read_b128 broadcast.
__global__ __launch_bounds__(128) void gemm_kernel(
    const float* __restrict__ X,
    const float* __restrict__ Wl, const float* __restrict__ bl,
    const float* __restrict__ Wr, const float* __restrict__ br,
    float* __restrict__ XL, float* __restrict__ XR) {
    __shared__ float WS[128][68];
    const int sel = blockIdx.x & 1;
    const float* __restrict__ W = sel ? Wr : Wl;
    const float* __restrict__ b = sel ? br : bl;
    float* __restrict__ OUT = sel ? XR : XL;

    for (int idx = threadIdx.x; idx < 64 * 128; idx += 128) {
        int k = idx >> 7, c = idx & 127;   // W is [k][c] row-major
        WS[c][k] = W[idx];
    }
    __syncthreads();

    const int node0 = (blockIdx.x >> 1) * 256;
    const int n0 = node0 + threadIdx.x;
    const int n1 = n0 + 128;

    float x0[64], x1[64];
    if (n0 < N_NODES) {
        const float4* p = (const float4*)(X + (size_t)n0 * D_IN);
        #pragma unroll
        for (int q = 0; q < 16; ++q) {
            float4 v = p[q];
            x0[4*q] = v.x; x0[4*q+1] = v.y; x0[4*q+2] = v.z; x0[4*q+3] = v.w;
        }
    } else {
        #pragma unroll
        for (int k = 0; k < 64; ++k) x0[k] = 0.0f;
    }
    if (n1 < N_NODES) {
        const float4* p = (const float4*)(X + (size_t)n1 * D_IN);
        #pragma unroll
        for (int q = 0; q < 16; ++q) {
            float4 v = p[q];
            x1[4*q] = v.x; x1[4*q+1] = v.y; x1[4*q+2] = v.z; x1[4*q+3] = v.w;
        }
    } else {
        #pragma unroll
        for (int k = 0; k < 64; ++k) x1[k] = 0.0f;
    }

    #pragma unroll 1
    for (int c0 = 0; c0 < 128; c0 += 4) {
        float acc0[4], acc1[4];
        #pragma unroll
        for (int i = 0; i < 4; ++i) {
            float bb = b[c0 + i];
            acc0[i] = bb; acc1[i] = bb;
        }
        #pragma unroll
        for (int k = 0; k < 64; k += 4) {
            #pragma unroll
            for (int i = 0; i < 4; ++i) {
                float4 wv = *(const float4*)&WS[c0 + i][k];  // broadcast read
                acc0[i] = fmaf(x0[k+3], wv.w, fmaf(x0[k+2], wv.z,
                          fmaf(x0[k+1], wv.y, fmaf(x0[k],   wv.x, acc0[i]))));
                acc1[i] = fmaf(x1[k+3], wv.w, fmaf(x1[k+2], wv.z,
                          fmaf(x1[k+1], wv.y, fmaf(x1[k],   wv.x, acc1[i]))));
            }
        }
        if (n0 < N_NODES)
            *(float4*)&OUT[(size_t)n0 * HC + c0] = make_float4(acc0[0], acc0[1], acc0[2], acc0[3]);
        if (n1 < N_NODES)
            *(float4*)&OUT[(size_t)n1 * HC + c0] = make_float4(acc1[0], acc1[1], acc1[2], acc1[3]);
    }
}

// ---------------- wave-per-node online-softmax aggregation ------------------
// lane l: head = l>>5, channels c = 2*(l&31), 2*(l&31)+1 within the head.
__global__ __launch_bounds__(256) void aggregate_kernel(
    const float* __restrict__ XL, const float* __restrict__ XR,
    const int* __restrict__ cnt, const int* __restrict__ tbl,
    const float* __restrict__ att, const float* __restrict__ bias,
    float* __restrict__ Y, int applyGelu) {
    const int v = (blockIdx.x * blockDim.x + threadIdx.x) >> 6;
    const int lane = threadIdx.x & 63;
    if (v >= N_NODES) return;
    const int half = lane >> 5;
    const int j = lane & 31;
    const int hc = half * 64 + 2 * j;

    const float2 xr_v = *(const float2*)(XR + (size_t)v * HC + hc);
    const float2 xl_v = *(const float2*)(XL + (size_t)v * HC + hc);
    const float2 a2   = *(const float2*)(att + hc);

    // self edge: z = xl[v] + xr[v]
    float z0 = xl_v.x + xr_v.x, z1 = xl_v.y + xr_v.y;
    float l0 = z0 > 0.0f ? z0 : 0.2f * z0;
    float l1 = z1 > 0.0f ? z1 : 0.2f * z1;
    float part = l0 * a2.x + l1 * a2.y;
    #pragma unroll
    for (int off = 16; off > 0; off >>= 1) part += __shfl_xor(part, off);

    float m = part, s = 1.0f;
    float acc0 = xl_v.x, acc1 = xl_v.y;

    int deg = cnt[v];
    if (deg > CAP) deg = CAP;
    int u_l = (lane < deg) ? tbl[v * CAP + lane] : 0;

    float2 xn = make_float2(0.0f, 0.0f);
    if (deg > 0) {
        int u0 = __shfl(u_l, 0);
        xn = *(const float2*)(XL + (size_t)u0 * HC + hc);
    }
    for (int i = 0; i < deg; ++i) {
        float2 xc = xn;
        if (i + 1 < deg) {
            int u = __shfl(u_l, i + 1);
            xn = *(const float2*)(XL + (size_t)u * HC + hc);  // prefetch next
        }
        z0 = xc.x + xr_v.x; z1 = xc.y + xr_v.y;
        l0 = z0 > 0.0f ? z0 : 0.2f * z0;
        l1 = z1 > 0.0f ? z1 : 0.2f * z1;
        part = l0 * a2.x + l1 * a2.y;
        #pragma unroll
        for (int off = 16; off > 0; off >>= 1) part += __shfl_xor(part, off);

        float mn = fmaxf(m, part);
        float we = __expf(part - mn);
        float sc = __expf(m - mn);
        s    = s * sc + we;
        acc0 = acc0 * sc + we * xc.x;
        acc1 = acc1 * sc + we * xc.y;
        m = mn;
    }

    float inv = 1.0f / (s + 1e-16f);
    float o0 = acc0 * inv, o1 = acc1 * inv;
    // mean over heads (H=2): combine halves
    o0 += __shfl_xor(o0, 32);
    o1 += __shfl_xor(o1, 32);
    o0 *= 0.5f; o1 *= 0.5f;
    if (half == 0) {
        int c = 2 * j;
        o0 += bias[c]; o1 += bias[c + 1];
        if (applyGelu) { o0 = gelu_f(o0); o1 = gelu_f(o1); }
        *(float2*)(Y + (size_t)v * 64 + c) = make_float2(o0, o1);
    }
}

extern "C" void kernel_launch(void* const* d_in, const int* in_sizes, int n_in,
                              void* d_out, int out_size, void* d_ws, size_t ws_size,
                              hipStream_t stream) {
    const float* X     = (const float*)d_in[0];
    const int*   edges = (const int*)d_in[1];
    const float* Wl    = (const float*)d_in[2];
    const float* bl    = (const float*)d_in[3];
    const float* Wr    = (const float*)d_in[4];
    const float* br    = (const float*)d_in[5];
    const float* att   = (const float*)d_in[6];
    const float* bias  = (const float*)d_in[7];

    char* ws = (char*)d_ws;
    float* XLb = (float*)ws;                                          // N*128 f32
    float* XRb = (float*)(ws + (size_t)N_NODES * HC * 4);             // N*128 f32
    float* Yb  = (float*)(ws + (size_t)N_NODES * HC * 8);             // N*64 f32
    int*   cnt = (int*)(ws + (size_t)N_NODES * HC * 8 + (size_t)N_NODES * 64 * 4);
    int*   tbl = cnt + N_NODES;                                       // N*CAP ints

    hipMemsetAsync(cnt, 0, N_NODES * sizeof(int), stream);
    scatter_kernel<<<(N_EDGES + 255) / 256, 256, 0, stream>>>(edges, cnt, tbl);

    const int gemm_grid = 2 * ((N_NODES + 255) / 256);
    const int agg_grid  = (N_NODES * 64 + 255) / 256;

    // layer 0
    gemm_kernel<<<gemm_grid, 128, 0, stream>>>(X, Wl, bl, Wr, br, XLb, XRb);
    aggregate_kernel<<<agg_grid, 256, 0, stream>>>(XLb, XRb, cnt, tbl, att, bias, Yb, 1);
    // layer 1
    gemm_kernel<<<gemm_grid, 128, 0, stream>>>(Yb, Wl + 8192, bl + 128, Wr + 8192, br + 128, XLb, XRb);
    aggregate_kernel<<<agg_grid, 256, 0, stream>>>(XLb, XRb, cnt, tbl, att + 128, bias + 64,
                                                   (float*)d_out, 0);
}

// Round 2
// 469.129 us; speedup vs baseline: 2.0960x; 2.0960x over previous
//
#include <hip/hip_runtime.h>
#include <math.h>

#define N_NODES 100000
#define N_EDGES 800000
#define D_IN    64
#define HC      128   // H*C
#define CAP     48    // max in-degree slots (Poisson(8): P(>48) ~ 0)

// tanh-approx gelu (jax.nn.gelu default approximate=True)
__device__ __forceinline__ float gelu_f(float x) {
    float x3 = x * x * x;
    float y  = 0.7978845608028654f * (x + 0.044715f * x3);
    float t = 1.0f - 2.0f / (__expf(2.0f * y) + 1.0f);
    return 0.5f * x * (1.0f + t);
}

// ---------------- CSR-by-capacity scatter (once; shared by both layers) ----
__global__ void scatter_kernel(const int* __restrict__ edges,
                               int* __restrict__ cnt, int* __restrict__ tbl) {
    int e = blockIdx.x * blockDim.x + threadIdx.x;
    if (e >= N_EDGES) return;
    int s = edges[e];            // src row
    int d = edges[N_EDGES + e];  // dst row
    int slot = atomicAdd(&cnt[d], 1);
    if (slot < CAP) tbl[d * CAP + slot] = s;
}

// ---------------- xl/xr GEMM: [N,64] @ [64,128] + b -------------------------
// 1 node per thread; x[64] in VGPRs (all constant-indexed -> no spill).
// W is indexed ONLY by loop constants -> uniform address -> compiler emits
// s_load; inner loop is v_fmac v,s,v (scalar W, vector x). No LDS.
// blockIdx parity selects (Wl,bl->XL) or (Wr,br->XR).
__global__ __launch_bounds__(256) void gemm_kernel(
    const float* __restrict__ X,
    const float* __restrict__ Wl, const float* __restrict__ bl,
    const float* __restrict__ Wr, const float* __restrict__ br,
    float* __restrict__ XL, float* __restrict__ XR) {
    const int sel = blockIdx.x & 1;
    const float* __restrict__ W = sel ? Wr : Wl;
    const float* __restrict__ b = sel ? br : bl;
    float* __restrict__ OUT = sel ? XR : XL;

    const int n = (blockIdx.x >> 1) * 256 + threadIdx.x;
    if (n >= N_NODES) return;

    float x[64];
    const float4* p = (const float4*)(X + (size_t)n * D_IN);
    #pragma unroll
    for (int q = 0; q < 16; ++q) {
        float4 v = p[q];
        x[4*q] = v.x; x[4*q+1] = v.y; x[4*q+2] = v.z; x[4*q+3] = v.w;
    }

    #pragma unroll 1
    for (int c0 = 0; c0 < 128; c0 += 8) {
        float acc[8];
        #pragma unroll
        for (int i = 0; i < 8; ++i) acc[i] = b[c0 + i];   // uniform -> s_load
        #pragma unroll
        for (int k = 0; k < 64; ++k) {                     // fully unrolled:
            #pragma unroll                                 // x[k] const-indexed
            for (int i = 0; i < 8; ++i)
                acc[i] = fmaf(x[k], W[k * HC + c0 + i], acc[i]);  // uniform W
        }
        *(float4*)&OUT[(size_t)n * HC + c0]     = make_float4(acc[0], acc[1], acc[2], acc[3]);
        *(float4*)&OUT[(size_t)n * HC + c0 + 4] = make_float4(acc[4], acc[5], acc[6], acc[7]);
    }
}

// ---------------- wave-per-node online-softmax aggregation ------------------
// lane l: head = l>>5, channels c = 2*(l&31), 2*(l&31)+1 within the head.
__global__ __launch_bounds__(256) void aggregate_kernel(
    const float* __restrict__ XL, const float* __restrict__ XR,
    const int* __restrict__ cnt, const int* __restrict__ tbl,
    const float* __restrict__ att, const float* __restrict__ bias,
    float* __restrict__ Y, int applyGelu) {
    const int v = (blockIdx.x * blockDim.x + threadIdx.x) >> 6;
    const int lane = threadIdx.x & 63;
    if (v >= N_NODES) return;
    const int half = lane >> 5;
    const int j = lane & 31;
    const int hc = half * 64 + 2 * j;

    const float2 xr_v = *(const float2*)(XR + (size_t)v * HC + hc);
    const float2 xl_v = *(const float2*)(XL + (size_t)v * HC + hc);
    const float2 a2   = *(const float2*)(att + hc);

    // self edge: z = xl[v] + xr[v]
    float z0 = xl_v.x + xr_v.x, z1 = xl_v.y + xr_v.y;
    float l0 = z0 > 0.0f ? z0 : 0.2f * z0;
    float l1 = z1 > 0.0f ? z1 : 0.2f * z1;
    float part = l0 * a2.x + l1 * a2.y;
    #pragma unroll
    for (int off = 16; off > 0; off >>= 1) part += __shfl_xor(part, off);

    float m = part, s = 1.0f;
    float acc0 = xl_v.x, acc1 = xl_v.y;

    int deg = cnt[v];
    if (deg > CAP) deg = CAP;
    int u_l = (lane < deg) ? tbl[v * CAP + lane] : 0;

    float2 xn = make_float2(0.0f, 0.0f);
    if (deg > 0) {
        int u0 = __shfl(u_l, 0);
        xn = *(const float2*)(XL + (size_t)u0 * HC + hc);
    }
    for (int i = 0; i < deg; ++i) {
        float2 xc = xn;
        if (i + 1 < deg) {
            int u = __shfl(u_l, i + 1);
            xn = *(const float2*)(XL + (size_t)u * HC + hc);  // prefetch next
        }
        z0 = xc.x + xr_v.x; z1 = xc.y + xr_v.y;
        l0 = z0 > 0.0f ? z0 : 0.2f * z0;
        l1 = z1 > 0.0f ? z1 : 0.2f * z1;
        part = l0 * a2.x + l1 * a2.y;
        #pragma unroll
        for (int off = 16; off > 0; off >>= 1) part += __shfl_xor(part, off);

        float mn = fmaxf(m, part);
        float we = __expf(part - mn);
        float sc = __expf(m - mn);
        s    = s * sc + we;
        acc0 = acc0 * sc + we * xc.x;
        acc1 = acc1 * sc + we * xc.y;
        m = mn;
    }

    float inv = 1.0f / (s + 1e-16f);
    float o0 = acc0 * inv, o1 = acc1 * inv;
    // mean over heads (H=2): combine halves
    o0 += __shfl_xor(o0, 32);
    o1 += __shfl_xor(o1, 32);
    o0 *= 0.5f; o1 *= 0.5f;
    if (half == 0) {
        int c = 2 * j;
        o0 += bias[c]; o1 += bias[c + 1];
        if (applyGelu) { o0 = gelu_f(o0); o1 = gelu_f(o1); }
        *(float2*)(Y + (size_t)v * 64 + c) = make_float2(o0, o1);
    }
}

extern "C" void kernel_launch(void* const* d_in, const int* in_sizes, int n_in,
                              void* d_out, int out_size, void* d_ws, size_t ws_size,
                              hipStream_t stream) {
    const float* X     = (const float*)d_in[0];
    const int*   edges = (const int*)d_in[1];
    const float* Wl    = (const float*)d_in[2];
    const float* bl    = (const float*)d_in[3];
    const float* Wr    = (const float*)d_in[4];
    const float* br    = (const float*)d_in[5];
    const float* att   = (const float*)d_in[6];
    const float* bias  = (const float*)d_in[7];

    char* ws = (char*)d_ws;
    float* XLb = (float*)ws;                                          // N*128 f32
    float* XRb = (float*)(ws + (size_t)N_NODES * HC * 4);             // N*128 f32
    float* Yb  = (float*)(ws + (size_t)N_NODES * HC * 8);             // N*64 f32
    int*   cnt = (int*)(ws + (size_t)N_NODES * HC * 8 + (size_t)N_NODES * 64 * 4);
    int*   tbl = cnt + N_NODES;                                       // N*CAP ints

    hipMemsetAsync(cnt, 0, N_NODES * sizeof(int), stream);
    scatter_kernel<<<(N_EDGES + 255) / 256, 256, 0, stream>>>(edges, cnt, tbl);

    const int gemm_grid = 2 * ((N_NODES + 255) / 256);
    const int agg_grid  = (N_NODES * 64 + 255) / 256;

    // layer 0
    gemm_kernel<<<gemm_grid, 256, 0, stream>>>(X, Wl, bl, Wr, br, XLb, XRb);
    aggregate_kernel<<<agg_grid, 256, 0, stream>>>(XLb, XRb, cnt, tbl, att, bias, Yb, 1);
    // layer 1
    gemm_kernel<<<gemm_grid, 256, 0, stream>>>(Yb, Wl + 8192, bl + 128, Wr + 8192, br + 128, XLb, XRb);
    aggregate_kernel<<<agg_grid, 256, 0, stream>>>(XLb, XRb, cnt, tbl, att + 128, bias + 64,
                                                   (float*)d_out, 0);
}

// Round 3
// 437.096 us; speedup vs baseline: 2.2496x; 1.0733x over previous
//
#include <hip/hip_runtime.h>
#include <math.h>

#define N_NODES 100000
#define N_EDGES 800000
#define D_IN    64
#define HC      128   // H*C
#define CAP     48    // max in-degree slots (Poisson(8): P(>48) ~ 0)

// tanh-approx gelu (jax.nn.gelu default approximate=True)
__device__ __forceinline__ float gelu_f(float x) {
    float x3 = x * x * x;
    float y  = 0.7978845608028654f * (x + 0.044715f * x3);
    float t = 1.0f - 2.0f / (__expf(2.0f * y) + 1.0f);
    return 0.5f * x * (1.0f + t);
}

// ---------------- CSR-by-capacity scatter (once; shared by both layers) ----
__global__ void scatter_kernel(const int* __restrict__ edges,
                               int* __restrict__ cnt, int* __restrict__ tbl) {
    int e = blockIdx.x * blockDim.x + threadIdx.x;
    if (e >= N_EDGES) return;
    int s = edges[e];            // src row
    int d = edges[N_EDGES + e];  // dst row
    int slot = atomicAdd(&cnt[d], 1);
    if (slot < CAP) tbl[d * CAP + slot] = s;
}

// ---------------- xl/xr GEMM: [N,64] @ [64,128] + b -------------------------
// 1 node per thread; x[64] in VGPRs (constant-indexed -> no spill). W indexed
// only by loop constants -> scalarized s_load; inner loop v_fmac v,s,v.
// Grid x4: bit0 = sel (Wl->XL / Wr->XR), bit1 = c-half (64 of 128 channels).
// c-chunk of 16 => 64B-aligned full-cache-line stores (no write amplification)
__global__ __launch_bounds__(256) void gemm_kernel(
    const float* __restrict__ X,
    const float* __restrict__ Wl, const float* __restrict__ bl,
    const float* __restrict__ Wr, const float* __restrict__ br,
    float* __restrict__ XL, float* __restrict__ XR) {
    const int sel   = blockIdx.x & 1;
    const int cbase = ((blockIdx.x >> 1) & 1) * 64;
    const float* __restrict__ W = sel ? Wr : Wl;
    const float* __restrict__ b = sel ? br : bl;
    float* __restrict__ OUT = sel ? XR : XL;

    const int n = (blockIdx.x >> 2) * 256 + threadIdx.x;
    if (n >= N_NODES) return;

    float x[64];
    const float4* p = (const float4*)(X + (size_t)n * D_IN);
    #pragma unroll
    for (int q = 0; q < 16; ++q) {
        float4 v = p[q];
        x[4*q] = v.x; x[4*q+1] = v.y; x[4*q+2] = v.z; x[4*q+3] = v.w;
    }

    #pragma unroll 1
    for (int c0 = cbase; c0 < cbase + 64; c0 += 16) {
        float acc[16];
        #pragma unroll
        for (int i = 0; i < 16; ++i) acc[i] = b[c0 + i];   // uniform -> s_load
        #pragma unroll
        for (int k = 0; k < 64; ++k) {                      // x[k] const-indexed
            #pragma unroll
            for (int i = 0; i < 16; ++i)
                acc[i] = fmaf(x[k], W[k * HC + c0 + i], acc[i]);  // uniform W
        }
        float* o = &OUT[(size_t)n * HC + c0];               // 64B-aligned line
        #pragma unroll
        for (int q = 0; q < 4; ++q)
            *(float4*)(o + 4 * q) = make_float4(acc[4*q], acc[4*q+1],
                                                acc[4*q+2], acc[4*q+3]);
    }
}

// ---------------- wave-per-node online-softmax aggregation ------------------
// lane l: head = l>>5, channels c = 2*(l&31), 2*(l&31)+1 within the head.
__global__ __launch_bounds__(256) void aggregate_kernel(
    const float* __restrict__ XL, const float* __restrict__ XR,
    const int* __restrict__ cnt, const int* __restrict__ tbl,
    const float* __restrict__ att, const float* __restrict__ bias,
    float* __restrict__ Y, int applyGelu) {
    const int v = (blockIdx.x * blockDim.x + threadIdx.x) >> 6;
    const int lane = threadIdx.x & 63;
    if (v >= N_NODES) return;
    const int half = lane >> 5;
    const int j = lane & 31;
    const int hc = half * 64 + 2 * j;

    const float2 xr_v = *(const float2*)(XR + (size_t)v * HC + hc);
    const float2 xl_v = *(const float2*)(XL + (size_t)v * HC + hc);
    const float2 a2   = *(const float2*)(att + hc);

    // self edge: z = xl[v] + xr[v]
    float z0 = xl_v.x + xr_v.x, z1 = xl_v.y + xr_v.y;
    float l0 = z0 > 0.0f ? z0 : 0.2f * z0;
    float l1 = z1 > 0.0f ? z1 : 0.2f * z1;
    float part = l0 * a2.x + l1 * a2.y;
    #pragma unroll
    for (int off = 16; off > 0; off >>= 1) part += __shfl_xor(part, off);

    float m = part, s = 1.0f;
    float acc0 = xl_v.x, acc1 = xl_v.y;

    int deg = cnt[v];
    if (deg > CAP) deg = CAP;
    int u_l = (lane < deg) ? tbl[v * CAP + lane] : 0;

    // depth-2 gather prefetch pipeline
    float2 x0 = make_float2(0.0f, 0.0f), x1 = make_float2(0.0f, 0.0f);
    if (deg > 0) {
        int u = __shfl(u_l, 0);
        x0 = *(const float2*)(XL + (size_t)u * HC + hc);
    }
    if (deg > 1) {
        int u = __shfl(u_l, 1);
        x1 = *(const float2*)(XL + (size_t)u * HC + hc);
    }
    for (int i = 0; i < deg; ++i) {
        float2 xc = x0;
        x0 = x1;
        if (i + 2 < deg) {
            int u = __shfl(u_l, i + 2);
            x1 = *(const float2*)(XL + (size_t)u * HC + hc);  // prefetch +2
        }
        z0 = xc.x + xr_v.x; z1 = xc.y + xr_v.y;
        l0 = z0 > 0.0f ? z0 : 0.2f * z0;
        l1 = z1 > 0.0f ? z1 : 0.2f * z1;
        part = l0 * a2.x + l1 * a2.y;
        #pragma unroll
        for (int off = 16; off > 0; off >>= 1) part += __shfl_xor(part, off);

        float mn = fmaxf(m, part);
        float we = __expf(part - mn);
        float sc = __expf(m - mn);
        s    = s * sc + we;
        acc0 = acc0 * sc + we * xc.x;
        acc1 = acc1 * sc + we * xc.y;
        m = mn;
    }

    float inv = 1.0f / (s + 1e-16f);
    float o0 = acc0 * inv, o1 = acc1 * inv;
    // mean over heads (H=2): combine halves
    o0 += __shfl_xor(o0, 32);
    o1 += __shfl_xor(o1, 32);
    o0 *= 0.5f; o1 *= 0.5f;
    if (half == 0) {
        int c = 2 * j;
        o0 += bias[c]; o1 += bias[c + 1];
        if (applyGelu) { o0 = gelu_f(o0); o1 = gelu_f(o1); }
        *(float2*)(Y + (size_t)v * 64 + c) = make_float2(o0, o1);
    }
}

extern "C" void kernel_launch(void* const* d_in, const int* in_sizes, int n_in,
                              void* d_out, int out_size, void* d_ws, size_t ws_size,
                              hipStream_t stream) {
    const float* X     = (const float*)d_in[0];
    const int*   edges = (const int*)d_in[1];
    const float* Wl    = (const float*)d_in[2];
    const float* bl    = (const float*)d_in[3];
    const float* Wr    = (const float*)d_in[4];
    const float* br    = (const float*)d_in[5];
    const float* att   = (const float*)d_in[6];
    const float* bias  = (const float*)d_in[7];

    char* ws = (char*)d_ws;
    float* XLb = (float*)ws;                                          // N*128 f32
    float* XRb = (float*)(ws + (size_t)N_NODES * HC * 4);             // N*128 f32
    float* Yb  = (float*)(ws + (size_t)N_NODES * HC * 8);             // N*64 f32
    int*   cnt = (int*)(ws + (size_t)N_NODES * HC * 8 + (size_t)N_NODES * 64 * 4);
    int*   tbl = cnt + N_NODES;                                       // N*CAP ints

    hipMemsetAsync(cnt, 0, N_NODES * sizeof(int), stream);
    scatter_kernel<<<(N_EDGES + 255) / 256, 256, 0, stream>>>(edges, cnt, tbl);

    const int gemm_grid = 4 * ((N_NODES + 255) / 256);
    const int agg_grid  = (N_NODES * 64 + 255) / 256;

    // layer 0
    gemm_kernel<<<gemm_grid, 256, 0, stream>>>(X, Wl, bl, Wr, br, XLb, XRb);
    aggregate_kernel<<<agg_grid, 256, 0, stream>>>(XLb, XRb, cnt, tbl, att, bias, Yb, 1);
    // layer 1
    gemm_kernel<<<gemm_grid, 256, 0, stream>>>(Yb, Wl + 8192, bl + 128, Wr + 8192, br + 128, XLb, XRb);
    aggregate_kernel<<<agg_grid, 256, 0, stream>>>(XLb, XRb, cnt, tbl, att + 128, bias + 64,
                                                   (float*)d_out, 0);
}